// Round 13
// baseline (331.542 us; speedup 1.0000x reference)
//
#include <hip/hip_runtime.h>
#include <hip/hip_bf16.h>
#include <stdint.h>

typedef short    s16x8  __attribute__((ext_vector_type(8)));
typedef __bf16   bf16x8 __attribute__((ext_vector_type(8)));
typedef float    f32x4  __attribute__((ext_vector_type(4)));

__device__ __forceinline__ unsigned short f2bf(float f) {
    union { float f; unsigned u; } v; v.f = f;
    unsigned r = v.u + 0x7FFFu + ((v.u >> 16) & 1u);
    return (unsigned short)(r >> 16);
}
__device__ __forceinline__ float bf2f(unsigned short s) {
    union { unsigned u; float f; } v; v.u = ((unsigned)s) << 16;
    return v.f;
}

__device__ __forceinline__ void gload16(const void* g, void* l) {
    __builtin_amdgcn_global_load_lds(
        (const __attribute__((address_space(1))) void*)(uintptr_t)g,
        (__attribute__((address_space(3))) void*)(uintptr_t)l,
        16, 0, 0);
}

// ---------------- fp32 -> bf16 conversion (weights only) --------------------
__global__ __launch_bounds__(256) void cvt_bf16(const float* __restrict__ in,
                                                unsigned short* __restrict__ out,
                                                int n4) {
    int i = blockIdx.x * blockDim.x + threadIdx.x;
    int stride = gridDim.x * blockDim.x;
    for (; i < n4; i += stride) {
        const float4 v = *(const float4*)(in + (size_t)i * 4);
        ushort4 o;
        o.x = f2bf(v.x); o.y = f2bf(v.y); o.z = f2bf(v.z); o.w = f2bf(v.w);
        *(ushort4*)(out + (size_t)i * 4) = o;
    }
}

// ---------------- GEMM1: R11 geometry + fused x conversion ------------------
// EXACT round-11 128x128 BK=64 structure (4 waves 2x2, 64x64/wave, NT=8,
// 1 syncthreads per window, T1/T2/T5, 2 blocks/CU). ONLY change: A-staging
// reads X as fp32 (2x float4/chunk, coalesced), converts in-register, and
// ds_writes to the SAME linear LDS offsets gload_lds used (consecutive lanes
// -> consecutive 16B -> conflict-free; layout identical to R11 = 0 conflicts).
// Deletes the cvt_x kernel and the xb HBM round-trip. A fp32 re-reads (12x
// per block-row) are L2-local: T1 swizzle puts consecutive wg (same bm) on
// the same XCD.
template<int K>
__global__ __launch_bounds__(256, 2) void gemm1f(
        const float* __restrict__ X,            // [M][K] fp32
        const unsigned short* __restrict__ B,   // [N][K] bf16 (W_qkv)
        const float* __restrict__ bias,         // [N] fp32
        unsigned short* __restrict__ C,         // [M][N] bf16
        int M, int N, int ntn) {
    constexpr int BM = 128, BN = 128, BK = 64, NT = K / BK;   // NT = 8
    __shared__ __align__(16) unsigned short As[2][BM * BK];   // 2 x 16 KiB
    __shared__ __align__(16) unsigned short Bs[2][BN * BK];   // 2 x 16 KiB
    const int tid  = threadIdx.x;
    const int lane = tid & 63;
    const int wv   = tid >> 6;                  // 4 waves
    const int nwg  = (int)gridDim.x;
    const int wg   = ((int)blockIdx.x & 7) * (nwg >> 3) + ((int)blockIdx.x >> 3);
    const int bm   = wg / ntn;
    const int bn   = wg % ntn;
    const int wr   = (wv >> 1) * 64;
    const int wc   = (wv & 1) * 64;
    const int lr   = lane & 15;
    const int ls   = lane >> 4;

    const float*          Ag = X + (size_t)bm * BM * K;
    const unsigned short* Bg = B + (size_t)bn * BN * K;

    // A: reg-staged fp32 -> bf16 -> ds_write (same layout as R11 gload path)
    auto stageA = [&](int t) {
        char* la = (char*)As[t & 1];
        #pragma unroll
        for (int p = 0; p < 4; ++p) {
            const int c     = p * 256 + tid;
            const int row   = c >> 3;                  // 8 x 16B chunks per row
            const int slot  = c & 7;
            const int gslot = slot ^ (row & 7);        // T2 involution
            const float* src = Ag + (size_t)row * K + t * BK + gslot * 8;
            const float4 v0 = *(const float4*)(src);
            const float4 v1 = *(const float4*)(src + 4);
            s16x8 o;
            o[0] = (short)f2bf(v0.x); o[1] = (short)f2bf(v0.y);
            o[2] = (short)f2bf(v0.z); o[3] = (short)f2bf(v0.w);
            o[4] = (short)f2bf(v1.x); o[5] = (short)f2bf(v1.y);
            o[6] = (short)f2bf(v1.z); o[7] = (short)f2bf(v1.w);
            *(s16x8*)(la + c * 16) = o;                // linear dest: no conflict
        }
    };
    auto stageB = [&](int t) {
        char* lb = (char*)Bs[t & 1];
        #pragma unroll
        for (int p = 0; p < 4; ++p) {
            const int c     = p * 256 + tid;
            const int row   = c >> 3;
            const int slot  = c & 7;
            const int gslot = slot ^ (row & 7);
            gload16(Bg + (size_t)row * K + t * BK + gslot * 8, lb + c * 16);
        }
    };
    auto frag = [&](const unsigned short* lds, int row, int ks) -> bf16x8 {
        const int slot = ks ^ (row & 7);
        return *(const bf16x8*)((const char*)lds + row * (BK * 2) + slot * 16);
    };

    f32x4 acc[4][4] = {};

    stageB(0); stageA(0);

    #pragma unroll
    for (int t = 0; t < NT; ++t) {
        asm volatile("s_waitcnt vmcnt(0)" ::: "memory");
        __syncthreads();               // slab t visible (vm + lgkm drained by
                                       // syncthreads for every wave)
        if (t + 1 < NT) { stageB(t + 1); stageA(t + 1); }

        bf16x8 af[2][4], bf[2][4];
        #pragma unroll
        for (int h = 0; h < 2; ++h) {
            #pragma unroll
            for (int m = 0; m < 4; ++m)
                af[h][m] = frag(As[t & 1], wr + m * 16 + lr, h * 4 + ls);
            #pragma unroll
            for (int n = 0; n < 4; ++n)
                bf[h][n] = frag(Bs[t & 1], wc + n * 16 + lr, h * 4 + ls);
        }

        __builtin_amdgcn_s_setprio(1);
        #pragma unroll
        for (int h = 0; h < 2; ++h)
            #pragma unroll
            for (int m = 0; m < 4; ++m)
                #pragma unroll
                for (int n = 0; n < 4; ++n)
                    acc[m][n] = __builtin_amdgcn_mfma_f32_16x16x32_bf16(
                        af[h][m], bf[h][n], acc[m][n], 0, 0, 0);
        __builtin_amdgcn_s_setprio(0);
    }

    const int r0 = bm * BM + wr + ls * 4;
    const int c0 = bn * BN + wc + lr;
    #pragma unroll
    for (int n = 0; n < 4; ++n) {
        const int gc = c0 + n * 16;
        const float bv = bias[gc];
        #pragma unroll
        for (int m = 0; m < 4; ++m) {
            #pragma unroll
            for (int j = 0; j < 4; ++j) {
                const int gr = r0 + m * 16 + j;
                C[(size_t)gr * N + gc] = f2bf(acc[m][n][j] + bv);
            }
        }
    }
}

// ---------------- 128x128 bf16 GEMM, BK=64 (round-11, GEMM2) ----------------
template<int K, bool OUT_BF16>
__global__ __launch_bounds__(256, 2) void gemm128(
        const unsigned short* __restrict__ A,
        const unsigned short* __restrict__ B,
        const float* __restrict__ bias,
        void* __restrict__ Cvoid,
        int M, int N, int ntn) {
    constexpr int BM = 128, BN = 128, BK = 64, NT = K / BK;
    __shared__ __align__(16) unsigned short As[2][BM * BK];
    __shared__ __align__(16) unsigned short Bs[2][BN * BK];
    const int tid  = threadIdx.x;
    const int lane = tid & 63;
    const int wv   = tid >> 6;
    const int nwg  = (int)gridDim.x;
    const int wg   = ((int)blockIdx.x & 7) * (nwg >> 3) + ((int)blockIdx.x >> 3);
    const int bm   = wg / ntn;
    const int bn   = wg % ntn;
    const int wr   = (wv >> 1) * 64;
    const int wc   = (wv & 1) * 64;
    const int lr   = lane & 15;
    const int ls   = lane >> 4;

    const unsigned short* Ag = A + (size_t)bm * BM * K;
    const unsigned short* Bg = B + (size_t)bn * BN * K;

    auto stage = [&](int t) {
        char* la = (char*)As[t & 1];
        char* lb = (char*)Bs[t & 1];
        #pragma unroll
        for (int p = 0; p < 4; ++p) {
            const int c     = p * 256 + tid;
            const int row   = c >> 3;
            const int slot  = c & 7;
            const int gslot = slot ^ (row & 7);
            gload16(Ag + (size_t)row * K + t * BK + gslot * 8, la + c * 16);
            gload16(Bg + (size_t)row * K + t * BK + gslot * 8, lb + c * 16);
        }
    };
    auto frag = [&](const unsigned short* lds, int row, int ks) -> bf16x8 {
        const int slot = ks ^ (row & 7);
        return *(const bf16x8*)((const char*)lds + row * (BK * 2) + slot * 16);
    };

    f32x4 acc[4][4] = {};

    stage(0);

    #pragma unroll
    for (int t = 0; t < NT; ++t) {
        asm volatile("s_waitcnt vmcnt(0)" ::: "memory");
        __syncthreads();
        if (t + 1 < NT) stage(t + 1);

        bf16x8 af[2][4], bf[2][4];
        #pragma unroll
        for (int h = 0; h < 2; ++h) {
            #pragma unroll
            for (int m = 0; m < 4; ++m)
                af[h][m] = frag(As[t & 1], wr + m * 16 + lr, h * 4 + ls);
            #pragma unroll
            for (int n = 0; n < 4; ++n)
                bf[h][n] = frag(Bs[t & 1], wc + n * 16 + lr, h * 4 + ls);
        }

        __builtin_amdgcn_s_setprio(1);
        #pragma unroll
        for (int h = 0; h < 2; ++h)
            #pragma unroll
            for (int m = 0; m < 4; ++m)
                #pragma unroll
                for (int n = 0; n < 4; ++n)
                    acc[m][n] = __builtin_amdgcn_mfma_f32_16x16x32_bf16(
                        af[h][m], bf[h][n], acc[m][n], 0, 0, 0);
        __builtin_amdgcn_s_setprio(0);
    }

    const int r0 = bm * BM + wr + ls * 4;
    const int c0 = bn * BN + wc + lr;
    #pragma unroll
    for (int n = 0; n < 4; ++n) {
        const int gc = c0 + n * 16;
        const float bv = bias[gc];
        #pragma unroll
        for (int m = 0; m < 4; ++m) {
            #pragma unroll
            for (int j = 0; j < 4; ++j) {
                const int gr = r0 + m * 16 + j;
                const float v = acc[m][n][j] + bv;
                if constexpr (OUT_BF16)
                    ((unsigned short*)Cvoid)[(size_t)gr * N + gc] = f2bf(v);
                else
                    ((float*)Cvoid)[(size_t)gr * N + gc] = v;
            }
        }
    }
}

// ---------------- per-token attention over heads (8x8 softmax) --------------
__global__ __launch_bounds__(256) void attn_heads(
        const unsigned short* __restrict__ qkv,   // [M][1536] bf16
        unsigned short* __restrict__ val,         // [M][512]  bf16
        int M) {
    const int t    = blockIdx.x * 4 + (threadIdx.x >> 6);
    const int lane = threadIdx.x & 63;
    const int h    = lane >> 3;
    const int c    = lane & 7;
    const unsigned short* base = qkv + (size_t)t * 1536;

    s16x8 q8 = *(const s16x8*)(base + h * 192 + c * 8);
    float qf[8];
    #pragma unroll
    for (int j = 0; j < 8; ++j) qf[j] = bf2f((unsigned short)q8[j]);

    float s[8];
    #pragma unroll
    for (int g = 0; g < 8; ++g) {
        s16x8 k8 = *(const s16x8*)(base + g * 192 + 64 + c * 8);
        float p = 0.f;
        #pragma unroll
        for (int j = 0; j < 8; ++j) p += qf[j] * bf2f((unsigned short)k8[j]);
        s[g] = p;
    }
    #pragma unroll
    for (int mask = 1; mask <= 4; mask <<= 1)
        #pragma unroll
        for (int g = 0; g < 8; ++g)
            s[g] += __shfl_xor(s[g], mask, 64);

    float mx = -1e30f;
    #pragma unroll
    for (int g = 0; g < 8; ++g) { s[g] *= 0.125f; mx = fmaxf(mx, s[g]); }
    float sum = 0.f;
    #pragma unroll
    for (int g = 0; g < 8; ++g) { s[g] = __expf(s[g] - mx); sum += s[g]; }
    const float inv = 1.f / sum;

    float acc[8] = {0.f,0.f,0.f,0.f,0.f,0.f,0.f,0.f};
    #pragma unroll
    for (int g = 0; g < 8; ++g) {
        s16x8 v8 = *(const s16x8*)(base + g * 192 + 128 + c * 8);
        const float ag = s[g] * inv;
        #pragma unroll
        for (int j = 0; j < 8; ++j) acc[j] += ag * bf2f((unsigned short)v8[j]);
    }
    s16x8 ov;
    #pragma unroll
    for (int j = 0; j < 8; ++j) ov[j] = (short)f2bf(acc[j]);
    *(s16x8*)(val + (size_t)t * 512 + h * 64 + c * 8) = ov;
}

// ---------------------------------------------------------------------------
extern "C" void kernel_launch(void* const* d_in, const int* in_sizes, int n_in,
                              void* d_out, int out_size, void* d_ws, size_t ws_size,
                              hipStream_t stream) {
    const float* x     = (const float*)d_in[0];
    const float* w_qkv = (const float*)d_in[1];
    const float* b_qkv = (const float*)d_in[2];
    const float* w_out = (const float*)d_in[3];
    const float* b_out = (const float*)d_in[4];
    float* out = (float*)d_out;

    const int DM = 512;
    const int M  = in_sizes[0] / DM;      // 61440 tokens

    unsigned short* wqkvb = (unsigned short*)d_ws;          // 1536*512
    unsigned short* woutb = wqkvb + (size_t)3 * DM * DM;    // 512*512
    unsigned short* qkvb  = woutb + (size_t)DM * DM;        // M*1536
    unsigned short* valb  = qkvb + (size_t)M * 3 * DM;      // M*512

    cvt_bf16<<<96, 256, 0, stream>>>(w_qkv, wqkvb, 3 * DM * DM / 4);
    cvt_bf16<<<32, 256, 0, stream>>>(w_out, woutb, DM * DM / 4);

    // GEMM1 (fused x-conversion, R11 geometry): grid 480*12=5760
    gemm1f<512><<<dim3((M / 128) * (3 * DM / 128)), 256, 0, stream>>>(
        x, wqkvb, b_qkv, qkvb, M, 3 * DM, 3 * DM / 128);

    // per-token attention over heads
    attn_heads<<<M / 4, 256, 0, stream>>>(qkvb, valb, M);

    // GEMM2: out[M][512] = val @ w_out^T + b_out (fp32 out). grid 480*4=1920
    gemm128<512, false><<<dim3((M / 128) * (DM / 128)), 256, 0, stream>>>(
        valb, woutb, b_out, out, M, DM, DM / 128);
}

// Round 14
// 307.866 us; speedup vs baseline: 1.0769x; 1.0769x over previous
//
#include <hip/hip_runtime.h>
#include <hip/hip_bf16.h>
#include <stdint.h>

typedef short    s16x8  __attribute__((ext_vector_type(8)));
typedef __bf16   bf16x8 __attribute__((ext_vector_type(8)));
typedef float    f32x4  __attribute__((ext_vector_type(4)));

__device__ __forceinline__ unsigned short f2bf(float f) {
    union { float f; unsigned u; } v; v.f = f;
    unsigned r = v.u + 0x7FFFu + ((v.u >> 16) & 1u);
    return (unsigned short)(r >> 16);
}
__device__ __forceinline__ float bf2f(unsigned short s) {
    union { unsigned u; float f; } v; v.u = ((unsigned)s) << 16;
    return v.f;
}

__device__ __forceinline__ void gload16(const void* g, void* l) {
    __builtin_amdgcn_global_load_lds(
        (const __attribute__((address_space(1))) void*)(uintptr_t)g,
        (__attribute__((address_space(3))) void*)(uintptr_t)l,
        16, 0, 0);
}

// ---------------- fp32 -> bf16 conversion (x and weights) -------------------
__global__ __launch_bounds__(256) void cvt_bf16(const float* __restrict__ in,
                                                unsigned short* __restrict__ out,
                                                int n4) {
    int i = blockIdx.x * blockDim.x + threadIdx.x;
    int stride = gridDim.x * blockDim.x;
    for (; i < n4; i += stride) {
        const float4 v = *(const float4*)(in + (size_t)i * 4);
        ushort4 o;
        o.x = f2bf(v.x); o.y = f2bf(v.y); o.z = f2bf(v.z); o.w = f2bf(v.w);
        *(ushort4*)(out + (size_t)i * 4) = o;
    }
}

// ---------------- 256x256 GEMM, 128x128 WAVE TILE (LDS-traffic-optimal) -----
// R13 post-mortem identified the binding resource: the LDS port. R11's 64x64
// wave tiles need 16 ds_read_b128/wave/window -> 2050 cyc/CU of port time vs
// 1240 cyc of MFMA demand. This kernel doubles FLOP per LDS byte by using
// 128x128 wave tiles (4 waves, 1 wave/SIMD, acc=256 VGPR, no spill at <512):
// per window: 32 reads + 128 MFMA per wave -> port ~2050 cyc/CU vs MFMA
// 2480 cyc/SIMD -> MFMA-bound. Unlike R7 (A direct from global, per-window
// vmem latency exposed), BOTH operands stage via gload_lds, and the vmcnt(0)
// wait targets loads issued a full window (~2500 cyc) earlier.
// BK=64, LDS 128 KiB dbuf, 1 block/CU. T1 XCD swizzle, T2 source-XOR swizzle
// (frag reads conflict-free in 16-lane phases — same algebra as R11, measured
// 0 conflicts), T5 setprio.
template<int K, bool OUT_BF16>
__global__ __launch_bounds__(256, 1) void gemm256w(
        const unsigned short* __restrict__ A,   // [M][K] bf16
        const unsigned short* __restrict__ B,   // [N][K] bf16
        const float* __restrict__ bias,         // [N] fp32
        void* __restrict__ Cvoid,               // [M][N] bf16 or fp32
        int M, int N, int ntn) {
    constexpr int BM = 256, BN = 256, BK = 64, NT = K / BK;   // NT = 8
    __shared__ __align__(16) unsigned short As[2][BM * BK];   // 2 x 32 KiB
    __shared__ __align__(16) unsigned short Bs[2][BN * BK];   // 2 x 32 KiB
    const int tid  = threadIdx.x;
    const int lane = tid & 63;
    const int wv   = tid >> 6;                  // 4 waves, 1 per SIMD
    const int nwg  = (int)gridDim.x;
    const int wg   = ((int)blockIdx.x & 7) * (nwg >> 3) + ((int)blockIdx.x >> 3);
    const int bm   = wg / ntn;
    const int bn   = wg % ntn;
    const int wr   = (wv >> 1) * 128;   // wave M-offset
    const int wc   = (wv & 1) * 128;    // wave N-offset
    const int lr   = lane & 15;
    const int ls   = lane >> 4;         // k-slot 0..3 within a 32-col half

    const unsigned short* Ag = A + (size_t)bm * BM * K;
    const unsigned short* Bg = B + (size_t)bn * BN * K;

    // Stage K-slab t: A and B 256x64 tiles (32 KiB = 2048 x 16B chunks each;
    // 8 chunks/thread/matrix). Linear LDS dest; T2 swizzle on global source:
    // 8 slots/row, gslot = slot ^ (row & 7) (involution, both sides).
    auto stage = [&](int t) {
        char* la = (char*)As[t & 1];
        char* lb = (char*)Bs[t & 1];
        #pragma unroll
        for (int p = 0; p < 8; ++p) {
            const int c     = p * 256 + tid;
            const int row   = c >> 3;                  // 8 x 16B chunks per row
            const int slot  = c & 7;
            const int gslot = slot ^ (row & 7);        // T2 involution
            gload16(Ag + (size_t)row * K + t * BK + gslot * 8, la + c * 16);
            gload16(Bg + (size_t)row * K + t * BK + gslot * 8, lb + c * 16);
        }
    };
    // Fragment read: logical k-slot ks (0..7 = half*4 + ls), physical XOR'd.
    // 16-lane phase groups hit 8 distinct slot-quads (2-way alias, free).
    auto frag = [&](const unsigned short* lds, int row, int ks) -> bf16x8 {
        const int slot = ks ^ (row & 7);
        return *(const bf16x8*)((const char*)lds + row * (BK * 2) + slot * 16);
    };

    f32x4 acc[8][8] = {};    // 256 VGPRs — the whole point

    stage(0);

    #pragma unroll
    for (int t = 0; t < NT; ++t) {
        asm volatile("s_waitcnt vmcnt(0)" ::: "memory");  // slab t landed
        __syncthreads();               // visible to all; prev slab consumed
        if (t + 1 < NT) stage(t + 1);  // dbuf partner: WAR-safe

        #pragma unroll
        for (int h = 0; h < 2; ++h) {  // two K=32 halves of the BK=64 slab
            bf16x8 af[8], bf[8];
            #pragma unroll
            for (int m = 0; m < 8; ++m)
                af[m] = frag(As[t & 1], wr + m * 16 + lr, h * 4 + ls);
            #pragma unroll
            for (int n = 0; n < 8; ++n)
                bf[n] = frag(Bs[t & 1], wc + n * 16 + lr, h * 4 + ls);

            __builtin_amdgcn_s_setprio(1);
            #pragma unroll
            for (int m = 0; m < 8; ++m)
                #pragma unroll
                for (int n = 0; n < 8; ++n)
                    acc[m][n] = __builtin_amdgcn_mfma_f32_16x16x32_bf16(
                        af[m], bf[n], acc[m][n], 0, 0, 0);
            __builtin_amdgcn_s_setprio(0);
        }
    }

    // epilogue: C/D layout col=lane&15, row=(lane>>4)*4+j (HW-verified)
    const int r0 = bm * BM + wr + ls * 4;
    const int c0 = bn * BN + wc + lr;
    #pragma unroll
    for (int n = 0; n < 8; ++n) {
        const int gc = c0 + n * 16;
        const float bv = bias[gc];
        #pragma unroll
        for (int m = 0; m < 8; ++m) {
            #pragma unroll
            for (int j = 0; j < 4; ++j) {
                const int gr = r0 + m * 16 + j;
                const float v = acc[m][n][j] + bv;
                if constexpr (OUT_BF16)
                    ((unsigned short*)Cvoid)[(size_t)gr * N + gc] = f2bf(v);
                else
                    ((float*)Cvoid)[(size_t)gr * N + gc] = v;
            }
        }
    }
}

// ---------------- per-token attention over heads (8x8 softmax) --------------
__global__ __launch_bounds__(256) void attn_heads(
        const unsigned short* __restrict__ qkv,   // [M][1536] bf16
        unsigned short* __restrict__ val,         // [M][512]  bf16
        int M) {
    const int t    = blockIdx.x * 4 + (threadIdx.x >> 6);
    const int lane = threadIdx.x & 63;
    const int h    = lane >> 3;
    const int c    = lane & 7;
    const unsigned short* base = qkv + (size_t)t * 1536;

    s16x8 q8 = *(const s16x8*)(base + h * 192 + c * 8);
    float qf[8];
    #pragma unroll
    for (int j = 0; j < 8; ++j) qf[j] = bf2f((unsigned short)q8[j]);

    float s[8];
    #pragma unroll
    for (int g = 0; g < 8; ++g) {
        s16x8 k8 = *(const s16x8*)(base + g * 192 + 64 + c * 8);
        float p = 0.f;
        #pragma unroll
        for (int j = 0; j < 8; ++j) p += qf[j] * bf2f((unsigned short)k8[j]);
        s[g] = p;
    }
    #pragma unroll
    for (int mask = 1; mask <= 4; mask <<= 1)
        #pragma unroll
        for (int g = 0; g < 8; ++g)
            s[g] += __shfl_xor(s[g], mask, 64);

    float mx = -1e30f;
    #pragma unroll
    for (int g = 0; g < 8; ++g) { s[g] *= 0.125f; mx = fmaxf(mx, s[g]); }
    float sum = 0.f;
    #pragma unroll
    for (int g = 0; g < 8; ++g) { s[g] = __expf(s[g] - mx); sum += s[g]; }
    const float inv = 1.f / sum;

    float acc[8] = {0.f,0.f,0.f,0.f,0.f,0.f,0.f,0.f};
    #pragma unroll
    for (int g = 0; g < 8; ++g) {
        s16x8 v8 = *(const s16x8*)(base + g * 192 + 128 + c * 8);
        const float ag = s[g] * inv;
        #pragma unroll
        for (int j = 0; j < 8; ++j) acc[j] += ag * bf2f((unsigned short)v8[j]);
    }
    s16x8 ov;
    #pragma unroll
    for (int j = 0; j < 8; ++j) ov[j] = (short)f2bf(acc[j]);
    *(s16x8*)(val + (size_t)t * 512 + h * 64 + c * 8) = ov;
}

// ---------------------------------------------------------------------------
extern "C" void kernel_launch(void* const* d_in, const int* in_sizes, int n_in,
                              void* d_out, int out_size, void* d_ws, size_t ws_size,
                              hipStream_t stream) {
    const float* x     = (const float*)d_in[0];
    const float* w_qkv = (const float*)d_in[1];
    const float* b_qkv = (const float*)d_in[2];
    const float* w_out = (const float*)d_in[3];
    const float* b_out = (const float*)d_in[4];
    float* out = (float*)d_out;

    const int DM = 512;
    const int M  = in_sizes[0] / DM;      // 61440 tokens

    unsigned short* xb    = (unsigned short*)d_ws;          // M*512
    unsigned short* wqkvb = xb + (size_t)M * DM;            // 1536*512
    unsigned short* woutb = wqkvb + (size_t)3 * DM * DM;    // 512*512
    unsigned short* qkvb  = woutb + (size_t)DM * DM;        // M*1536
    unsigned short* valb  = qkvb + (size_t)M * 3 * DM;      // M*512

    cvt_bf16<<<2048, 256, 0, stream>>>(x, xb, M * DM / 4);
    cvt_bf16<<<96,   256, 0, stream>>>(w_qkv, wqkvb, 3 * DM * DM / 4);
    cvt_bf16<<<32,   256, 0, stream>>>(w_out, woutb, DM * DM / 4);

    // GEMM1: qkv[M][1536] = x @ w_qkv^T + b_qkv (bf16 out). grid 240*6=1440
    gemm256w<512, true><<<dim3((M / 256) * (3 * DM / 256)), 256, 0, stream>>>(
        xb, wqkvb, b_qkv, qkvb, M, 3 * DM, 3 * DM / 256);

    // per-token attention over heads
    attn_heads<<<M / 4, 256, 0, stream>>>(qkvb, valb, M);

    // GEMM2: out[M][512] = val @ w_out^T + b_out (fp32 out). grid 240*2=480
    gemm256w<512, false><<<dim3((M / 256) * (DM / 256)), 256, 0, stream>>>(
        valb, woutb, b_out, out, M, DM, DM / 256);
}